// Round 16
// baseline (225.847 us; speedup 1.0000x reference)
//
#include <hip/hip_runtime.h>

// GCN regression: out = relu( dinv⊙(A_hat @ (dinv⊙(x@W1^T))) + b1 ) @ W2^T + b2
// R11: gemm v3 — x tile in LDS (32 KB, swizzled), W1 read directly from
//      global (L1/L2-resident, 16-lane broadcast); 5 blocks/CU.
//   1. init_kernel  : bcur[b] = b*CAPB
//   2. part_kernel  : per-block(8192 edges) LDS hist + scan + 1 atomic/bucket
//   3. bscan2_kernel: scan -> compact csr offsets boff
//   4. csrb2_kernel : per-bucket node hist+scan (offs/degc), LDS scatter -> CSR
//   5. gemm_kernel  : g = dinv ⊙ (x @ W1^T) stored bf16
//   6. agg_kernel   : wave per node; s_load csr indices; 16 gathers in flight

typedef unsigned int u32;
typedef unsigned short u16;

#define PK 8192      // edges per partition block
#define EPT (PK/256) // edges per thread in part (32)
#define CAPB 9216    // slot capacity per 256-node bucket (mean 8192, +11 sigma)

__device__ __forceinline__ u16 f2bf(float f) {
    u32 b = __float_as_uint(f);
    b += 0x7FFF + ((b >> 16) & 1);
    return (u16)(b >> 16);
}
__device__ __forceinline__ float bf2f(u16 u) {
    return __uint_as_float(((u32)u) << 16);
}

// tile element index (in dwords) for (row r, col k) of a [64][128] f32 tile:
// 16B slot = r*32 + (q ^ swz(r)); staging writes and 4ty+i broadcast reads
// are both bank-conflict-free.
__device__ __forceinline__ int tidx(int r, int k) {
    int sw = (((r & 3) << 3) | ((r >> 2) & 7));
    return (((r << 5) + ((k >> 2) ^ sw)) << 2) + (k & 3);
}

// ---- 1. slotted cursor init ----
__global__ __launch_bounds__(512) void init_kernel(int* __restrict__ bcur, int NB) {
    int t = threadIdx.x;
    if (t < NB) bcur[t] = t * CAPB;
}

// ---- 2. chunked partition: 1 global atomic per bucket per block ----
__global__ __launch_bounds__(256) void part_kernel(const int* __restrict__ src,
                                                   const int* __restrict__ dst,
                                                   int* __restrict__ bcur,
                                                   u32* __restrict__ ebuf, int E, int NB) {
    __shared__ u32 stage[PK];     // 32 KB
    __shared__ u16 sbid[PK];      // 16 KB
    __shared__ int h[512], loff[512], gbase[512], cur[512];
    int t = threadIdx.x;
    int e0 = blockIdx.x * PK;
    int e1 = e0 + PK; if (e1 > E) e1 = E;
    int cnt = e1 - e0;
    for (int i = t; i < 512; i += 256) { h[i] = 0; cur[i] = 0; }
    __syncthreads();
    int dreg[EPT];
#pragma unroll
    for (int i = 0; i < EPT; ++i) {
        int e = e0 + i * 256 + t;
        dreg[i] = (e < e1) ? dst[e] : -1;
        if (dreg[i] >= 0) atomicAdd(&h[dreg[i] >> 8], 1);
    }
    __syncthreads();
    if (t < 64) {                 // wave 0: scan 512 slots, carry across chunks
        int carry = 0;
        for (int c = 0; c < 8; ++c) {
            int idx = c * 64 + t;
            int v = h[idx], incl = v;
            for (int d2 = 1; d2 < 64; d2 <<= 1) {
                int o = __shfl_up(incl, d2);
                if (t >= d2) incl += o;
            }
            loff[idx] = carry + incl - v;
            carry += __shfl(incl, 63);
        }
    }
    __syncthreads();
    for (int idx = t; idx < NB; idx += 256)
        gbase[idx] = atomicAdd(&bcur[idx], h[idx]);
    __syncthreads();
#pragma unroll
    for (int i = 0; i < EPT; ++i) {
        int d = dreg[i];
        if (d >= 0) {
            int e = e0 + i * 256 + t;
            int s = src[e];
            int bk = d >> 8;
            int r = atomicAdd(&cur[bk], 1);
            int p = loff[bk] + r;
            stage[p] = ((u32)(d & 255) << 17) | (u32)s;
            sbid[p] = (u16)bk;
        }
    }
    __syncthreads();
    for (int i = t; i < cnt; i += 256) {        // coalesced runs per bucket
        int bk = sbid[i];
        ebuf[gbase[bk] + (i - loff[bk])] = stage[i];
    }
}

// ---- 3. compact csr offsets from slotted cursors (NB <= 512) ----
__global__ __launch_bounds__(512) void bscan2_kernel(const int* __restrict__ bcur,
                                                     int* __restrict__ boff,
                                                     int NB, int E) {
    __shared__ int buf[2][512];
    int t = threadIdx.x;
    int v = (t < NB) ? (bcur[t] - t * CAPB) : 0;
    buf[0][t] = v;
    __syncthreads();
    int pi = 0;
    for (int d = 1; d < 512; d <<= 1) {
        int val = buf[pi][t];
        if (t >= d) val += buf[pi][t - d];
        buf[pi ^ 1][t] = val;
        pi ^= 1;
        __syncthreads();
    }
    if (t < NB) boff[t] = buf[pi][t] - v;
    if (t == 0) boff[NB] = E;
}

// ---- 4. per-bucket CSR build + offs/degc ----
__global__ __launch_bounds__(256) void csrb2_kernel(const u32* __restrict__ ebuf,
                                                    const int* __restrict__ boff,
                                                    int* __restrict__ csr,
                                                    int* __restrict__ offs,
                                                    int* __restrict__ degc,
                                                    int N) {
    __shared__ u32 stage[CAPB];   // 36 KB
    __shared__ int h2[256], lofs[256], cur2[256];
    int t = threadIdx.x;
    int b = blockIdx.x;
    int base = b << 8;
    int c0 = boff[b];
    int cnt = boff[b + 1] - c0;
    int e0 = b * CAPB;
    h2[t] = 0; cur2[t] = 0;
    __syncthreads();
    for (int e = t; e < cnt; e += 256) atomicAdd(&h2[(int)(ebuf[e0 + e] >> 17)], 1);
    __syncthreads();
    if (t < 64) {
        int carry = 0;
        for (int c = 0; c < 4; ++c) {
            int idx = c * 64 + t;
            int v = h2[idx], incl = v;
            for (int d2 = 1; d2 < 64; d2 <<= 1) {
                int o = __shfl_up(incl, d2);
                if (t >= d2) incl += o;
            }
            lofs[idx] = carry + incl - v;
            carry += __shfl(incl, 63);
        }
    }
    __syncthreads();
    int n = base + t;
    if (n < N) { offs[n] = c0 + lofs[t]; degc[n] = h2[t]; }
    if (cnt <= CAPB) {
        for (int e = t; e < cnt; e += 256) {
            u32 pk = ebuf[e0 + e];
            int dl = (int)(pk >> 17);
            int r = atomicAdd(&cur2[dl], 1);
            stage[lofs[dl] + r] = pk & 0x1FFFF;
        }
        __syncthreads();
        for (int e = t; e < cnt; e += 256) csr[c0 + e] = (int)stage[e];
    } else {  // statistically unreachable fallback
        for (int e = t; e < cnt; e += 256) {
            u32 pk = ebuf[e0 + e];
            int dl = (int)(pk >> 17);
            int r = atomicAdd(&cur2[dl], 1);
            csr[c0 + lofs[dl] + r] = (int)(pk & 0x1FFFF);
        }
    }
}

// ---- 5. g = dinv * (x @ W1^T), bf16 out; x LDS-staged, W1 from global ----
__global__ __launch_bounds__(256) void gemm_kernel(const float* __restrict__ x,
                                                   const float* __restrict__ W1,
                                                   const int* __restrict__ degc,
                                                   u16* __restrict__ gb, int N) {
    __shared__ float xl[64 * 128];   // 32 KB, swizzled via tidx
    int t = threadIdx.x;
    int nbase = blockIdx.x * 64;

    // stage x tile: straight row-major float4 copies into swizzled slots
#pragma unroll
    for (int it = 0; it < 8; ++it) {
        int qi = it * 256 + t;
        int r = qi >> 5;           // row 0..63
        int q = qi & 31;           // k-quad 0..31
        int n = nbase + r;
        float4 v = make_float4(0.f, 0.f, 0.f, 0.f);
        if (n < N) v = *(const float4*)&x[(size_t)n * 128 + (q << 2)];
        *(float4*)&xl[tidx(r, q << 2)] = v;
    }
    __syncthreads();

    int tx = t & 15;   // channel group: c = tx*4 .. +3
    int ty = t >> 4;   // node group:    n = ty*4 .. +3
    const float* w0 = W1 + (tx << 2) * 128;   // 4 rows, stride 128 floats
    float acc[4][4] = {};
#pragma unroll 2
    for (int kq = 0; kq < 32; ++kq) {
        int k4 = kq << 2;
        float4 xa[4], wa[4];
#pragma unroll
        for (int i = 0; i < 4; ++i) xa[i] = *(const float4*)&xl[tidx((ty << 2) + i, k4)];
#pragma unroll
        for (int j = 0; j < 4; ++j) wa[j] = *(const float4*)&w0[j * 128 + k4];
#pragma unroll
        for (int i = 0; i < 4; ++i)
#pragma unroll
            for (int j = 0; j < 4; ++j) {
                acc[i][j] = fmaf(xa[i].x, wa[j].x, acc[i][j]);
                acc[i][j] = fmaf(xa[i].y, wa[j].y, acc[i][j]);
                acc[i][j] = fmaf(xa[i].z, wa[j].z, acc[i][j]);
                acc[i][j] = fmaf(xa[i].w, wa[j].w, acc[i][j]);
            }
    }

#pragma unroll
    for (int i = 0; i < 4; ++i) {
        int n = nbase + (ty << 2) + i;
        if (n < N) {
            float dv = rsqrtf((float)(degc[n] + 1));
            ushort4 o;
            o.x = f2bf(dv * acc[i][0]);
            o.y = f2bf(dv * acc[i][1]);
            o.z = f2bf(dv * acc[i][2]);
            o.w = f2bf(dv * acc[i][3]);
            *(ushort4*)&gb[(size_t)n * 64 + (tx << 2)] = o;
        }
    }
}

// ---- 6. wave per node: s_load_dwordx16 indices, 16 gathers in flight ----
__global__ __launch_bounds__(256) void agg_kernel(const u16* __restrict__ gb,
                                                  const int* __restrict__ csr,
                                                  const int* __restrict__ offs,
                                                  const int* __restrict__ degc,
                                                  const float* __restrict__ W2,
                                                  const float* __restrict__ b1,
                                                  const float* __restrict__ b2,
                                                  float* __restrict__ out, int N) {
    int wid = blockIdx.x * 4 + (threadIdx.x >> 6);
    int lane = threadIdx.x & 63;
    if (wid >= N) return;
    // wave-uniform scalars -> SGPR: csr reads become s_load, row base SALU
    int off = __builtin_amdgcn_readfirstlane(offs[wid]);
    int cnt = __builtin_amdgcn_readfirstlane(degc[wid]);
    const u16* gbl = gb + lane;               // per-lane channel base
    float acc = bf2f(gbl[(size_t)wid * 64]);  // self loop
    int j = 0;
    for (; j + 16 <= cnt; j += 16) {
        float v[16];
#pragma unroll
        for (int k = 0; k < 16; ++k) {
            int s = csr[off + j + k];         // uniform addr -> s_load_dwordx16
            v[k] = bf2f(gbl[(size_t)s * 64]);
        }
        float s01 = (v[0] + v[1]) + (v[2] + v[3]);
        float s23 = (v[4] + v[5]) + (v[6] + v[7]);
        float s45 = (v[8] + v[9]) + (v[10] + v[11]);
        float s67 = (v[12] + v[13]) + (v[14] + v[15]);
        acc += (s01 + s23) + (s45 + s67);
    }
    for (; j + 4 <= cnt; j += 4) {
        float v[4];
#pragma unroll
        for (int k = 0; k < 4; ++k) {
            int s = csr[off + j + k];
            v[k] = bf2f(gbl[(size_t)s * 64]);
        }
        acc += (v[0] + v[1]) + (v[2] + v[3]);
    }
    for (; j < cnt; ++j) {
        int s = csr[off + j];
        acc += bf2f(gbl[(size_t)s * 64]);
    }
    float dv = rsqrtf((float)(cnt + 1));
    float val = fmaxf(dv * acc + b1[lane], 0.f) * W2[lane];
#pragma unroll
    for (int o = 32; o >= 1; o >>= 1) val += __shfl_xor(val, o);
    if (lane == 0) out[wid] = val + b2[0];
}

extern "C" void kernel_launch(void* const* d_in, const int* in_sizes, int n_in,
                              void* d_out, int out_size, void* d_ws, size_t ws_size,
                              hipStream_t stream) {
    const float* x  = (const float*)d_in[0];
    const int*   ei = (const int*)d_in[1];
    const float* W1 = (const float*)d_in[2];
    const float* b1 = (const float*)d_in[3];
    const float* W2 = (const float*)d_in[4];
    const float* b2 = (const float*)d_in[5];
    float* out = (float*)d_out;

    int N = in_sizes[0] / 128;
    int E = in_sizes[1] / 2;
    const int* src = ei;
    const int* dst = ei + E;
    int NB = (N + 255) >> 8;           // 391 (<= 512)
    int NBLK = (E + PK - 1) / PK;      // 391

    char* ws = (char*)d_ws;
    int* bcur = (int*)(ws + 0x000000);   // NB ints
    int* boff = (int*)(ws + 0x004000);   // NB+1 ints
    int* degc = (int*)(ws + 0x010000);   // N ints
    int* offs = (int*)(ws + 0x080000);   // N ints
    u32* ebuf = (u32*)(ws + 0x100000);   // NB*CAPB u32 (13.8 MB); dead after csrb2
    u16* gb   = (u16*)(ws + 0x100000);   // N*64 bf16 (12.8 MB) ALIASES ebuf
    int* csr  = (int*)(ws + 0xF00000);   // E ints (12.8 MB) -> ends ~27.2 MB

    init_kernel<<<1, 512, 0, stream>>>(bcur, NB);
    part_kernel<<<NBLK, 256, 0, stream>>>(src, dst, bcur, ebuf, E, NB);
    bscan2_kernel<<<1, 512, 0, stream>>>(bcur, boff, NB, E);
    csrb2_kernel<<<NB, 256, 0, stream>>>(ebuf, boff, csr, offs, degc, N);
    gemm_kernel<<<(N + 63) / 64, 256, 0, stream>>>(x, W1, degc, gb, N);
    agg_kernel<<<(N + 3) / 4, 256, 0, stream>>>(gb, csr, offs, degc, W2, b1, b2, out, N);
}

// Round 17
// 144.622 us; speedup vs baseline: 1.5616x; 1.5616x over previous
//
#include <hip/hip_runtime.h>

// GCN regression: out = relu( dinv⊙(A_hat @ (dinv⊙(x@W1^T))) + b1 ) @ W2^T + b2
// R12: MFMA gemm (16x16x32 bf16, no LDS) + bf16 W1 pre-pass.
//   1. init_kernel  : bcur[b] = b*CAPB
//   2. wcvt_kernel  : W1 f32 -> bf16 (16 KB, one block)
//   3. part_kernel  : per-block(8192 edges) LDS hist + scan + 1 atomic/bucket
//   4. bscan2_kernel: scan -> compact csr offsets boff
//   5. csrb2_kernel : per-bucket node hist+scan (offs/degc), LDS scatter -> CSR
//   6. gemm_kernel  : g = dinv ⊙ (x @ W1^T) via mfma_f32_16x16x32_bf16,
//                     A/B frags loaded straight from global (no LDS/barriers)
//   7. agg_kernel   : wave per node; s_load csr indices; 16 gathers in flight

typedef unsigned int u32;
typedef unsigned short u16;
typedef __attribute__((ext_vector_type(8))) short bf16x8;
typedef __attribute__((ext_vector_type(4))) float f32x4;

#define PK 8192      // edges per partition block
#define EPT (PK/256) // edges per thread in part (32)
#define CAPB 9216    // slot capacity per 256-node bucket (mean 8192, +11 sigma)

__device__ __forceinline__ u16 f2bf(float f) {
    u32 b = __float_as_uint(f);
    b += 0x7FFF + ((b >> 16) & 1);   // RNE
    return (u16)(b >> 16);
}
__device__ __forceinline__ float bf2f(u16 u) {
    return __uint_as_float(((u32)u) << 16);
}
__device__ __forceinline__ bf16x8 pack8(float4 lo, float4 hi) {
    bf16x8 o;
    o[0] = (short)f2bf(lo.x); o[1] = (short)f2bf(lo.y);
    o[2] = (short)f2bf(lo.z); o[3] = (short)f2bf(lo.w);
    o[4] = (short)f2bf(hi.x); o[5] = (short)f2bf(hi.y);
    o[6] = (short)f2bf(hi.z); o[7] = (short)f2bf(hi.w);
    return o;
}

// ---- 1. slotted cursor init ----
__global__ __launch_bounds__(512) void init_kernel(int* __restrict__ bcur, int NB) {
    int t = threadIdx.x;
    if (t < NB) bcur[t] = t * CAPB;
}

// ---- 2. W1 -> bf16 (8192 elements) ----
__global__ __launch_bounds__(256) void wcvt_kernel(const float* __restrict__ W1,
                                                   u16* __restrict__ wbf) {
    int t = threadIdx.x;
#pragma unroll
    for (int i = 0; i < 32; ++i) wbf[i * 256 + t] = f2bf(W1[i * 256 + t]);
}

// ---- 3. chunked partition: 1 global atomic per bucket per block ----
__global__ __launch_bounds__(256) void part_kernel(const int* __restrict__ src,
                                                   const int* __restrict__ dst,
                                                   int* __restrict__ bcur,
                                                   u32* __restrict__ ebuf, int E, int NB) {
    __shared__ u32 stage[PK];     // 32 KB
    __shared__ u16 sbid[PK];      // 16 KB
    __shared__ int h[512], loff[512], gbase[512], cur[512];
    int t = threadIdx.x;
    int e0 = blockIdx.x * PK;
    int e1 = e0 + PK; if (e1 > E) e1 = E;
    int cnt = e1 - e0;
    for (int i = t; i < 512; i += 256) { h[i] = 0; cur[i] = 0; }
    __syncthreads();
    int dreg[EPT];
#pragma unroll
    for (int i = 0; i < EPT; ++i) {
        int e = e0 + i * 256 + t;
        dreg[i] = (e < e1) ? dst[e] : -1;
        if (dreg[i] >= 0) atomicAdd(&h[dreg[i] >> 8], 1);
    }
    __syncthreads();
    if (t < 64) {                 // wave 0: scan 512 slots, carry across chunks
        int carry = 0;
        for (int c = 0; c < 8; ++c) {
            int idx = c * 64 + t;
            int v = h[idx], incl = v;
            for (int d2 = 1; d2 < 64; d2 <<= 1) {
                int o = __shfl_up(incl, d2);
                if (t >= d2) incl += o;
            }
            loff[idx] = carry + incl - v;
            carry += __shfl(incl, 63);
        }
    }
    __syncthreads();
    for (int idx = t; idx < NB; idx += 256)
        gbase[idx] = atomicAdd(&bcur[idx], h[idx]);
    __syncthreads();
#pragma unroll
    for (int i = 0; i < EPT; ++i) {
        int d = dreg[i];
        if (d >= 0) {
            int e = e0 + i * 256 + t;
            int s = src[e];
            int bk = d >> 8;
            int r = atomicAdd(&cur[bk], 1);
            int p = loff[bk] + r;
            stage[p] = ((u32)(d & 255) << 17) | (u32)s;
            sbid[p] = (u16)bk;
        }
    }
    __syncthreads();
    for (int i = t; i < cnt; i += 256) {        // coalesced runs per bucket
        int bk = sbid[i];
        ebuf[gbase[bk] + (i - loff[bk])] = stage[i];
    }
}

// ---- 4. compact csr offsets from slotted cursors (NB <= 512) ----
__global__ __launch_bounds__(512) void bscan2_kernel(const int* __restrict__ bcur,
                                                     int* __restrict__ boff,
                                                     int NB, int E) {
    __shared__ int buf[2][512];
    int t = threadIdx.x;
    int v = (t < NB) ? (bcur[t] - t * CAPB) : 0;
    buf[0][t] = v;
    __syncthreads();
    int pi = 0;
    for (int d = 1; d < 512; d <<= 1) {
        int val = buf[pi][t];
        if (t >= d) val += buf[pi][t - d];
        buf[pi ^ 1][t] = val;
        pi ^= 1;
        __syncthreads();
    }
    if (t < NB) boff[t] = buf[pi][t] - v;
    if (t == 0) boff[NB] = E;
}

// ---- 5. per-bucket CSR build + offs/degc ----
__global__ __launch_bounds__(256) void csrb2_kernel(const u32* __restrict__ ebuf,
                                                    const int* __restrict__ boff,
                                                    int* __restrict__ csr,
                                                    int* __restrict__ offs,
                                                    int* __restrict__ degc,
                                                    int N) {
    __shared__ u32 stage[CAPB];   // 36 KB
    __shared__ int h2[256], lofs[256], cur2[256];
    int t = threadIdx.x;
    int b = blockIdx.x;
    int base = b << 8;
    int c0 = boff[b];
    int cnt = boff[b + 1] - c0;
    int e0 = b * CAPB;
    h2[t] = 0; cur2[t] = 0;
    __syncthreads();
    for (int e = t; e < cnt; e += 256) atomicAdd(&h2[(int)(ebuf[e0 + e] >> 17)], 1);
    __syncthreads();
    if (t < 64) {
        int carry = 0;
        for (int c = 0; c < 4; ++c) {
            int idx = c * 64 + t;
            int v = h2[idx], incl = v;
            for (int d2 = 1; d2 < 64; d2 <<= 1) {
                int o = __shfl_up(incl, d2);
                if (t >= d2) incl += o;
            }
            lofs[idx] = carry + incl - v;
            carry += __shfl(incl, 63);
        }
    }
    __syncthreads();
    int n = base + t;
    if (n < N) { offs[n] = c0 + lofs[t]; degc[n] = h2[t]; }
    if (cnt <= CAPB) {
        for (int e = t; e < cnt; e += 256) {
            u32 pk = ebuf[e0 + e];
            int dl = (int)(pk >> 17);
            int r = atomicAdd(&cur2[dl], 1);
            stage[lofs[dl] + r] = pk & 0x1FFFF;
        }
        __syncthreads();
        for (int e = t; e < cnt; e += 256) csr[c0 + e] = (int)stage[e];
    } else {  // statistically unreachable fallback
        for (int e = t; e < cnt; e += 256) {
            u32 pk = ebuf[e0 + e];
            int dl = (int)(pk >> 17);
            int r = atomicAdd(&cur2[dl], 1);
            csr[c0 + lofs[dl] + r] = (int)(pk & 0x1FFFF);
        }
    }
}

// ---- 6. g = dinv * (x @ W1^T) via MFMA; frags direct from global ----
// wave w handles nodes n0..n0+15; A lane l: x[n0+(l&15)][ks*32+(l>>4)*8..+8]
// B lane l: wbf[(ct*16+(l&15))*128 + ks*32+(l>>4)*8..+8] (bf16, contiguous)
// D: col(channel-within-ct)=lane&15, row(node-within-16)=(lane>>4)*4+reg
__global__ __launch_bounds__(256) void gemm_kernel(const float* __restrict__ x,
                                                   const u16* __restrict__ wbf,
                                                   const int* __restrict__ degc,
                                                   u16* __restrict__ gb, int N) {
    int t = threadIdx.x;
    int lane = t & 63;
    int wv = t >> 6;
    int n0 = blockIdx.x * 64 + wv * 16;
    int r = lane & 15;
    int g = lane >> 4;

    int nr = n0 + r; if (nr >= N) nr = N - 1;      // clamp: garbage rows unused
    const float* xrow = x + (size_t)nr * 128 + g * 8;
    bf16x8 afr[4];
#pragma unroll
    for (int ks = 0; ks < 4; ++ks) {
        float4 lo = *(const float4*)(xrow + ks * 32);
        float4 hi = *(const float4*)(xrow + ks * 32 + 4);
        afr[ks] = pack8(lo, hi);
    }

    f32x4 acc[4] = {f32x4{0.f,0.f,0.f,0.f}, f32x4{0.f,0.f,0.f,0.f},
                    f32x4{0.f,0.f,0.f,0.f}, f32x4{0.f,0.f,0.f,0.f}};
#pragma unroll
    for (int ct = 0; ct < 4; ++ct) {
        const u16* wrow = wbf + (ct * 16 + r) * 128 + g * 8;
#pragma unroll
        for (int ks = 0; ks < 4; ++ks) {
            bf16x8 bfr = *(const bf16x8*)(wrow + ks * 32);
            acc[ct] = __builtin_amdgcn_mfma_f32_16x16x32_bf16(afr[ks], bfr, acc[ct], 0, 0, 0);
        }
    }

#pragma unroll
    for (int reg = 0; reg < 4; ++reg) {
        int n = n0 + g * 4 + reg;
        if (n < N) {
            float dv = rsqrtf((float)(degc[n] + 1));
#pragma unroll
            for (int ct = 0; ct < 4; ++ct)
                gb[(size_t)n * 64 + ct * 16 + r] = f2bf(dv * acc[ct][reg]);
        }
    }
}

// ---- 7. wave per node: s_load_dwordx16 indices, 16 gathers in flight ----
__global__ __launch_bounds__(256) void agg_kernel(const u16* __restrict__ gb,
                                                  const int* __restrict__ csr,
                                                  const int* __restrict__ offs,
                                                  const int* __restrict__ degc,
                                                  const float* __restrict__ W2,
                                                  const float* __restrict__ b1,
                                                  const float* __restrict__ b2,
                                                  float* __restrict__ out, int N) {
    int wid = blockIdx.x * 4 + (threadIdx.x >> 6);
    int lane = threadIdx.x & 63;
    if (wid >= N) return;
    // wave-uniform scalars -> SGPR: csr reads become s_load, row base SALU
    int off = __builtin_amdgcn_readfirstlane(offs[wid]);
    int cnt = __builtin_amdgcn_readfirstlane(degc[wid]);
    const u16* gbl = gb + lane;               // per-lane channel base
    float acc = bf2f(gbl[(size_t)wid * 64]);  // self loop
    int j = 0;
    for (; j + 16 <= cnt; j += 16) {
        float v[16];
#pragma unroll
        for (int k = 0; k < 16; ++k) {
            int s = csr[off + j + k];         // uniform addr -> s_load_dwordx16
            v[k] = bf2f(gbl[(size_t)s * 64]);
        }
        float s01 = (v[0] + v[1]) + (v[2] + v[3]);
        float s23 = (v[4] + v[5]) + (v[6] + v[7]);
        float s45 = (v[8] + v[9]) + (v[10] + v[11]);
        float s67 = (v[12] + v[13]) + (v[14] + v[15]);
        acc += (s01 + s23) + (s45 + s67);
    }
    for (; j + 4 <= cnt; j += 4) {
        float v[4];
#pragma unroll
        for (int k = 0; k < 4; ++k) {
            int s = csr[off + j + k];
            v[k] = bf2f(gbl[(size_t)s * 64]);
        }
        acc += (v[0] + v[1]) + (v[2] + v[3]);
    }
    for (; j < cnt; ++j) {
        int s = csr[off + j];
        acc += bf2f(gbl[(size_t)s * 64]);
    }
    float dv = rsqrtf((float)(cnt + 1));
    float val = fmaxf(dv * acc + b1[lane], 0.f) * W2[lane];
#pragma unroll
    for (int o = 32; o >= 1; o >>= 1) val += __shfl_xor(val, o);
    if (lane == 0) out[wid] = val + b2[0];
}

extern "C" void kernel_launch(void* const* d_in, const int* in_sizes, int n_in,
                              void* d_out, int out_size, void* d_ws, size_t ws_size,
                              hipStream_t stream) {
    const float* x  = (const float*)d_in[0];
    const int*   ei = (const int*)d_in[1];
    const float* W1 = (const float*)d_in[2];
    const float* b1 = (const float*)d_in[3];
    const float* W2 = (const float*)d_in[4];
    const float* b2 = (const float*)d_in[5];
    float* out = (float*)d_out;

    int N = in_sizes[0] / 128;
    int E = in_sizes[1] / 2;
    const int* src = ei;
    const int* dst = ei + E;
    int NB = (N + 255) >> 8;           // 391 (<= 512)
    int NBLK = (E + PK - 1) / PK;      // 391

    char* ws = (char*)d_ws;
    int* bcur = (int*)(ws + 0x000000);   // NB ints
    int* boff = (int*)(ws + 0x004000);   // NB+1 ints
    int* degc = (int*)(ws + 0x010000);   // N ints
    int* offs = (int*)(ws + 0x080000);   // N ints (ends ~0xE1A80)
    u16* wbf  = (u16*)(ws + 0x0F0000);   // 64*128 bf16 (16 KB)
    u32* ebuf = (u32*)(ws + 0x100000);   // NB*CAPB u32 (13.8 MB); dead after csrb2
    u16* gb   = (u16*)(ws + 0x100000);   // N*64 bf16 (12.8 MB) ALIASES ebuf
    int* csr  = (int*)(ws + 0xF00000);   // E ints (12.8 MB) -> ends ~27.2 MB

    init_kernel<<<1, 512, 0, stream>>>(bcur, NB);
    wcvt_kernel<<<1, 256, 0, stream>>>(W1, wbf);
    part_kernel<<<NBLK, 256, 0, stream>>>(src, dst, bcur, ebuf, E, NB);
    bscan2_kernel<<<1, 512, 0, stream>>>(bcur, boff, NB, E);
    csrb2_kernel<<<NB, 256, 0, stream>>>(ebuf, boff, csr, offs, degc, N);
    gemm_kernel<<<(N + 63) / 64, 256, 0, stream>>>(x, wbf, degc, gb, N);
    agg_kernel<<<(N + 3) / 4, 256, 0, stream>>>(gb, csr, offs, degc, W2, b1, b2, out, N);
}

// Round 18
// 134.211 us; speedup vs baseline: 1.6828x; 1.0776x over previous
//
#include <hip/hip_runtime.h>
#include <hip/hip_bf16.h>

// GCN regression: out = relu( dinv⊙(A_hat @ (dinv⊙(x@W1^T))) + b1 ) @ W2^T + b2
// R13: part 512t/PK4096 (3-4 blocks/CU), csrb2 512t, gemm hw bf16 cvt,
//      merged setup kernel.
//   1. setup_kernel : bcur[b]=b*CAPB  +  W1 f32->bf16
//   2. part_kernel  : per-block(4096 edges) LDS hist + scan + 1 atomic/bucket
//   3. bscan2_kernel: scan -> compact csr offsets boff
//   4. csrb2_kernel : per-bucket node hist+scan (offs/degc), LDS scatter -> CSR
//   5. gemm_kernel  : g = dinv ⊙ (x @ W1^T) via mfma_f32_16x16x32_bf16
//   6. agg_kernel   : wave per node; s_load csr indices; 16 gathers in flight

typedef unsigned int u32;
typedef unsigned short u16;
typedef __attribute__((ext_vector_type(8))) short bf16x8;
typedef __attribute__((ext_vector_type(4))) float f32x4;

#define PK 4096      // edges per partition block
#define PTH 512      // part threads
#define EPT (PK/PTH) // 8
#define CAPB 9216    // slot capacity per 256-node bucket (mean 8192, +11 sigma)

__device__ __forceinline__ short f2bf(float f) {   // RNE via hardware cvt
    __hip_bfloat16 h = __float2bfloat16(f);
    return *reinterpret_cast<short*>(&h);
}
__device__ __forceinline__ float bf2f(u16 u) {
    return __uint_as_float(((u32)u) << 16);
}
__device__ __forceinline__ bf16x8 pack8(float4 lo, float4 hi) {
    bf16x8 o;
    o[0] = f2bf(lo.x); o[1] = f2bf(lo.y); o[2] = f2bf(lo.z); o[3] = f2bf(lo.w);
    o[4] = f2bf(hi.x); o[5] = f2bf(hi.y); o[6] = f2bf(hi.z); o[7] = f2bf(hi.w);
    return o;
}

// ---- 1. setup: slotted cursors + W1 -> bf16 ----
__global__ __launch_bounds__(512) void setup_kernel(int* __restrict__ bcur,
                                                    const float* __restrict__ W1,
                                                    u16* __restrict__ wbf, int NB) {
    int t = threadIdx.x;
    if (blockIdx.x == 0) {
        if (t < NB) bcur[t] = t * CAPB;
    } else {
#pragma unroll
        for (int i = 0; i < 16; ++i) wbf[i * 512 + t] = (u16)f2bf(W1[i * 512 + t]);
    }
}

// ---- 2. chunked partition: 1 global atomic per bucket per block ----
__global__ __launch_bounds__(PTH) void part_kernel(const int* __restrict__ src,
                                                   const int* __restrict__ dst,
                                                   int* __restrict__ bcur,
                                                   u32* __restrict__ ebuf, int E, int NB) {
    __shared__ u32 stage[PK];     // 16 KB
    __shared__ u16 sbid[PK];      // 8 KB
    __shared__ int h[512], loff[512], gbase[512], cur[512];   // 8 KB
    int t = threadIdx.x;
    int e0 = blockIdx.x * PK;
    int e1 = e0 + PK; if (e1 > E) e1 = E;
    int cnt = e1 - e0;
    h[t] = 0; cur[t] = 0;
    __syncthreads();
    int dreg[EPT];
#pragma unroll
    for (int i = 0; i < EPT; ++i) {
        int e = e0 + i * PTH + t;
        dreg[i] = (e < e1) ? dst[e] : -1;
        if (dreg[i] >= 0) atomicAdd(&h[dreg[i] >> 8], 1);
    }
    __syncthreads();
    if (t < 64) {                 // wave 0: scan 512 slots, carry across chunks
        int carry = 0;
        for (int c = 0; c < 8; ++c) {
            int idx = c * 64 + t;
            int v = h[idx], incl = v;
            for (int d2 = 1; d2 < 64; d2 <<= 1) {
                int o = __shfl_up(incl, d2);
                if (t >= d2) incl += o;
            }
            loff[idx] = carry + incl - v;
            carry += __shfl(incl, 63);
        }
    }
    __syncthreads();
    if (t < NB) gbase[t] = atomicAdd(&bcur[t], h[t]);
    __syncthreads();
#pragma unroll
    for (int i = 0; i < EPT; ++i) {
        int d = dreg[i];
        if (d >= 0) {
            int e = e0 + i * PTH + t;
            int s = src[e];
            int bk = d >> 8;
            int r = atomicAdd(&cur[bk], 1);
            int p = loff[bk] + r;
            stage[p] = ((u32)(d & 255) << 17) | (u32)s;
            sbid[p] = (u16)bk;
        }
    }
    __syncthreads();
    for (int i = t; i < cnt; i += PTH) {        // coalesced runs per bucket
        int bk = sbid[i];
        ebuf[gbase[bk] + (i - loff[bk])] = stage[i];
    }
}

// ---- 3. compact csr offsets from slotted cursors (NB <= 512) ----
__global__ __launch_bounds__(512) void bscan2_kernel(const int* __restrict__ bcur,
                                                     int* __restrict__ boff,
                                                     int NB, int E) {
    __shared__ int buf[2][512];
    int t = threadIdx.x;
    int v = (t < NB) ? (bcur[t] - t * CAPB) : 0;
    buf[0][t] = v;
    __syncthreads();
    int pi = 0;
    for (int d = 1; d < 512; d <<= 1) {
        int val = buf[pi][t];
        if (t >= d) val += buf[pi][t - d];
        buf[pi ^ 1][t] = val;
        pi ^= 1;
        __syncthreads();
    }
    if (t < NB) boff[t] = buf[pi][t] - v;
    if (t == 0) boff[NB] = E;
}

// ---- 4. per-bucket CSR build + offs/degc (512 threads) ----
__global__ __launch_bounds__(512) void csrb2_kernel(const u32* __restrict__ ebuf,
                                                    const int* __restrict__ boff,
                                                    int* __restrict__ csr,
                                                    int* __restrict__ offs,
                                                    int* __restrict__ degc,
                                                    int N) {
    __shared__ u32 stage[CAPB];   // 36 KB
    __shared__ int h2[256], lofs[256], cur2[256];
    int t = threadIdx.x;
    int b = blockIdx.x;
    int base = b << 8;
    int c0 = boff[b];
    int cnt = boff[b + 1] - c0;
    int e0 = b * CAPB;
    if (t < 256) { h2[t] = 0; cur2[t] = 0; }
    __syncthreads();
    for (int e = t; e < cnt; e += 512) atomicAdd(&h2[(int)(ebuf[e0 + e] >> 17)], 1);
    __syncthreads();
    if (t < 64) {
        int carry = 0;
        for (int c = 0; c < 4; ++c) {
            int idx = c * 64 + t;
            int v = h2[idx], incl = v;
            for (int d2 = 1; d2 < 64; d2 <<= 1) {
                int o = __shfl_up(incl, d2);
                if (t >= d2) incl += o;
            }
            lofs[idx] = carry + incl - v;
            carry += __shfl(incl, 63);
        }
    }
    __syncthreads();
    if (t < 256) {
        int n = base + t;
        if (n < N) { offs[n] = c0 + lofs[t]; degc[n] = h2[t]; }
    }
    if (cnt <= CAPB) {
        for (int e = t; e < cnt; e += 512) {
            u32 pk = ebuf[e0 + e];
            int dl = (int)(pk >> 17);
            int r = atomicAdd(&cur2[dl], 1);
            stage[lofs[dl] + r] = pk & 0x1FFFF;
        }
        __syncthreads();
        for (int e = t; e < cnt; e += 512) csr[c0 + e] = (int)stage[e];
    } else {  // statistically unreachable fallback
        for (int e = t; e < cnt; e += 512) {
            u32 pk = ebuf[e0 + e];
            int dl = (int)(pk >> 17);
            int r = atomicAdd(&cur2[dl], 1);
            csr[c0 + lofs[dl] + r] = (int)(pk & 0x1FFFF);
        }
    }
}

// ---- 5. g = dinv * (x @ W1^T) via MFMA; frags direct from global ----
// wave w: nodes n0..n0+15; A lane l: x[n0+(l&15)][ks*32+(l>>4)*8..+8]
// B lane l: wbf[(ct*16+(l&15))*128 + ks*32+(l>>4)*8..+8]
// D: col=lane&15 (channel), row=(lane>>4)*4+reg (node)
__global__ __launch_bounds__(256) void gemm_kernel(const float* __restrict__ x,
                                                   const u16* __restrict__ wbf,
                                                   const int* __restrict__ degc,
                                                   u16* __restrict__ gb, int N) {
    int t = threadIdx.x;
    int lane = t & 63;
    int wv = t >> 6;
    int n0 = blockIdx.x * 64 + wv * 16;
    int r = lane & 15;
    int g = lane >> 4;

    int nr = n0 + r; if (nr >= N) nr = N - 1;      // clamp: garbage rows unused
    const float* xrow = x + (size_t)nr * 128 + g * 8;
    bf16x8 afr[4];
#pragma unroll
    for (int ks = 0; ks < 4; ++ks) {
        float4 lo = *(const float4*)(xrow + ks * 32);
        float4 hi = *(const float4*)(xrow + ks * 32 + 4);
        afr[ks] = pack8(lo, hi);
    }

    f32x4 acc[4] = {f32x4{0.f,0.f,0.f,0.f}, f32x4{0.f,0.f,0.f,0.f},
                    f32x4{0.f,0.f,0.f,0.f}, f32x4{0.f,0.f,0.f,0.f}};
#pragma unroll
    for (int ct = 0; ct < 4; ++ct) {
        const u16* wrow = wbf + (ct * 16 + r) * 128 + g * 8;
#pragma unroll
        for (int ks = 0; ks < 4; ++ks) {
            bf16x8 bfr = *(const bf16x8*)(wrow + ks * 32);
            acc[ct] = __builtin_amdgcn_mfma_f32_16x16x32_bf16(afr[ks], bfr, acc[ct], 0, 0, 0);
        }
    }

#pragma unroll
    for (int reg = 0; reg < 4; ++reg) {
        int n = n0 + g * 4 + reg;
        if (n < N) {
            float dv = rsqrtf((float)(degc[n] + 1));
#pragma unroll
            for (int ct = 0; ct < 4; ++ct)
                gb[(size_t)n * 64 + ct * 16 + r] = (u16)f2bf(dv * acc[ct][reg]);
        }
    }
}

// ---- 6. wave per node: s_load_dwordx16 indices, 16 gathers in flight ----
__global__ __launch_bounds__(256) void agg_kernel(const u16* __restrict__ gb,
                                                  const int* __restrict__ csr,
                                                  const int* __restrict__ offs,
                                                  const int* __restrict__ degc,
                                                  const float* __restrict__ W2,
                                                  const float* __restrict__ b1,
                                                  const float* __restrict__ b2,
                                                  float* __restrict__ out, int N) {
    int wid = blockIdx.x * 4 + (threadIdx.x >> 6);
    int lane = threadIdx.x & 63;
    if (wid >= N) return;
    // wave-uniform scalars -> SGPR: csr reads become s_load, row base SALU
    int off = __builtin_amdgcn_readfirstlane(offs[wid]);
    int cnt = __builtin_amdgcn_readfirstlane(degc[wid]);
    const u16* gbl = gb + lane;               // per-lane channel base
    float acc = bf2f(gbl[(size_t)wid * 64]);  // self loop
    int j = 0;
    for (; j + 16 <= cnt; j += 16) {
        float v[16];
#pragma unroll
        for (int k = 0; k < 16; ++k) {
            int s = csr[off + j + k];         // uniform addr -> s_load_dwordx16
            v[k] = bf2f(gbl[(size_t)s * 64]);
        }
        float s01 = (v[0] + v[1]) + (v[2] + v[3]);
        float s23 = (v[4] + v[5]) + (v[6] + v[7]);
        float s45 = (v[8] + v[9]) + (v[10] + v[11]);
        float s67 = (v[12] + v[13]) + (v[14] + v[15]);
        acc += (s01 + s23) + (s45 + s67);
    }
    for (; j + 4 <= cnt; j += 4) {
        float v[4];
#pragma unroll
        for (int k = 0; k < 4; ++k) {
            int s = csr[off + j + k];
            v[k] = bf2f(gbl[(size_t)s * 64]);
        }
        acc += (v[0] + v[1]) + (v[2] + v[3]);
    }
    for (; j < cnt; ++j) {
        int s = csr[off + j];
        acc += bf2f(gbl[(size_t)s * 64]);
    }
    float dv = rsqrtf((float)(cnt + 1));
    float val = fmaxf(dv * acc + b1[lane], 0.f) * W2[lane];
#pragma unroll
    for (int o = 32; o >= 1; o >>= 1) val += __shfl_xor(val, o);
    if (lane == 0) out[wid] = val + b2[0];
}

extern "C" void kernel_launch(void* const* d_in, const int* in_sizes, int n_in,
                              void* d_out, int out_size, void* d_ws, size_t ws_size,
                              hipStream_t stream) {
    const float* x  = (const float*)d_in[0];
    const int*   ei = (const int*)d_in[1];
    const float* W1 = (const float*)d_in[2];
    const float* b1 = (const float*)d_in[3];
    const float* W2 = (const float*)d_in[4];
    const float* b2 = (const float*)d_in[5];
    float* out = (float*)d_out;

    int N = in_sizes[0] / 128;
    int E = in_sizes[1] / 2;
    const int* src = ei;
    const int* dst = ei + E;
    int NB = (N + 255) >> 8;           // 391 (<= 512)
    int NBLK = (E + PK - 1) / PK;      // 782

    char* ws = (char*)d_ws;
    int* bcur = (int*)(ws + 0x000000);   // NB ints
    int* boff = (int*)(ws + 0x004000);   // NB+1 ints
    int* degc = (int*)(ws + 0x010000);   // N ints
    int* offs = (int*)(ws + 0x080000);   // N ints
    u16* wbf  = (u16*)(ws + 0x0F0000);   // 64*128 bf16 (16 KB)
    u32* ebuf = (u32*)(ws + 0x100000);   // NB*CAPB u32 (13.8 MB); dead after csrb2
    u16* gb   = (u16*)(ws + 0x100000);   // N*64 bf16 (12.8 MB) ALIASES ebuf
    int* csr  = (int*)(ws + 0xF00000);   // E ints (12.8 MB) -> ends ~27.2 MB

    setup_kernel<<<2, 512, 0, stream>>>(bcur, W1, wbf, NB);
    part_kernel<<<NBLK, PTH, 0, stream>>>(src, dst, bcur, ebuf, E, NB);
    bscan2_kernel<<<1, 512, 0, stream>>>(bcur, boff, NB, E);
    csrb2_kernel<<<NB, 512, 0, stream>>>(ebuf, boff, csr, offs, degc, N);
    gemm_kernel<<<(N + 63) / 64, 256, 0, stream>>>(x, wbf, degc, gb, N);
    agg_kernel<<<(N + 3) / 4, 256, 0, stream>>>(gb, csr, offs, degc, W2, b1, b2, out, N);
}